// Round 3
// baseline (639.646 us; speedup 1.0000x reference)
//
#include <hip/hip_runtime.h>

// Soft-circuit FP32 scale-by-2^k, reduced to integer bit ops.
// Row layout (element e <-> bit e of packed word):
//   bit 0 = sign; bits 1..8 = exponent (elem 1 = MSB); bits 9..31 = mantissa.
//
// R2: one ROW per thread. Eliminates the 6 ds_bpermute ops/thread of the
// shuffle-based assembly (R0) and amortizes wave overhead over 8x more
// traffic. Loads/stores are stride-128B per instruction, but each wave's
// 8 unrolled accesses cover one contiguous 8KB block -> L1/L2 coalesce.
// Bit extraction: inputs are exactly 0.0f/1.0f, so bit = (u >> 23) & 1.

__device__ __forceinline__ unsigned rev8(unsigned v) {
    return __builtin_bitreverse32(v) >> 24;
}

__global__ __launch_bounds__(256) void spike_scale_row_kernel(
        const uint4* __restrict__ x4,
        const uint4* __restrict__ k4,
        float4* __restrict__ o4,
        int nrows) {
    int row = blockIdx.x * 256 + threadIdx.x;
    if (row >= nrows) return;

    const uint4* xr = x4 + (size_t)row * 8;
    const uint4* kr = k4 + (size_t)row * 8;

    uint4 vx[8], vk[8];
#pragma unroll
    for (int j = 0; j < 8; ++j) vx[j] = xr[j];
#pragma unroll
    for (int j = 0; j < 8; ++j) vk[j] = kr[j];

    // pack row bits: element 4j+c lives in vx[j] component c
    unsigned xw = 0u, kw = 0u;
#pragma unroll
    for (int j = 0; j < 8; ++j) {
        unsigned nx = ((vx[j].x >> 23) & 1u)
                    | (((vx[j].y >> 23) & 1u) << 1)
                    | (((vx[j].z >> 23) & 1u) << 2)
                    | (((vx[j].w >> 23) & 1u) << 3);
        unsigned nk = ((vk[j].x >> 23) & 1u)
                    | (((vk[j].y >> 23) & 1u) << 1)
                    | (((vk[j].z >> 23) & 1u) << 2)
                    | (((vk[j].w >> 23) & 1u) << 3);
        xw |= nx << (4 * j);
        kw |= nk << (4 * j);
    }

    // decode k: ek = exponent as int, val = 8-bit significand 1.m7
    unsigned ek   = rev8((kw >> 1) & 0xFFu);
    unsigned val  = 0x80u | (__builtin_bitreverse32((kw >> 9) & 0x7Fu) >> 25);
    unsigned s    = (ek - 127u) & 7u;
    unsigned kabs = val >> (7u - s);
    unsigned kfin = (kw & 1u) ? ((0u - kabs) & 0xFFu) : kabs;

    unsigned ex   = rev8((xw >> 1) & 0xFFu);
    unsigned enew = (ex + kfin) & 0xFFu;

    unsigned scaled = (xw & 1u) | (rev8(enew) << 1) | (xw & 0xFFFFFE00u);
    unsigned res    = ((kw & ~1u) == 0u) ? xw : scaled;

    // unpack 32 bits -> 32 floats, 8 float4 stores
    float4* orow = o4 + (size_t)row * 8;
#pragma unroll
    for (int j = 0; j < 8; ++j) {
        float4 o;
        o.x = ((res >> (4 * j + 0)) & 1u) ? 1.0f : 0.0f;
        o.y = ((res >> (4 * j + 1)) & 1u) ? 1.0f : 0.0f;
        o.z = ((res >> (4 * j + 2)) & 1u) ? 1.0f : 0.0f;
        o.w = ((res >> (4 * j + 3)) & 1u) ? 1.0f : 0.0f;
        orow[j] = o;
    }
}

extern "C" void kernel_launch(void* const* d_in, const int* in_sizes, int n_in,
                              void* d_out, int out_size, void* d_ws, size_t ws_size,
                              hipStream_t stream) {
    const uint4* x4 = (const uint4*)d_in[0];
    const uint4* k4 = (const uint4*)d_in[1];
    float4* o4 = (float4*)d_out;

    int n_elems = in_sizes[0];          // N * 32
    int nrows   = n_elems / 32;         // 2,097,152 rows
    int blocks  = (nrows + 255) / 256;  // 8192 blocks

    spike_scale_row_kernel<<<blocks, 256, 0, stream>>>(x4, k4, o4, nrows);
}

// Round 5
// 583.526 us; speedup vs baseline: 1.0962x; 1.0962x over previous
//
#include <hip/hip_runtime.h>

// Soft-circuit FP32 scale-by-2^k, reduced to integer bit ops.
// Row layout (element e <-> bit e of packed word):
//   bit 0 = sign; bits 1..8 = exponent (elem 1 = MSB); bits 9..31 = mantissa.
//
// R4: same as R3 (R0 structure + block-local x4 unroll + NT stores), with
// the nontemporal store going through a native clang vector type (the HIP
// float4 class is not accepted by __builtin_nontemporal_store).

#define UNROLL 4

typedef float vfloat4 __attribute__((ext_vector_type(4)));

__device__ __forceinline__ unsigned rev8(unsigned v) {
    return __builtin_bitreverse32(v) >> 24;
}

__device__ __forceinline__ unsigned nib4(uint4 v) {
    // elements are exactly 0.0f or 1.0f -> bit 23 of the float pattern
    return ((v.x >> 23) & 1u)
         | (((v.y >> 23) & 1u) << 1)
         | (((v.z >> 23) & 1u) << 2)
         | (((v.w >> 23) & 1u) << 3);
}

__global__ __launch_bounds__(256) void spike_scale_kernel(
        const uint4* __restrict__ x4,
        const uint4* __restrict__ k4,
        vfloat4* __restrict__ o4) {
    int tileBase = blockIdx.x * (256 * UNROLL);
    int t = threadIdx.x;

    unsigned base = (unsigned)(t & 7) * 4u;  // nibble position in the row

    uint4 vx[UNROLL], vk[UNROLL];
#pragma unroll
    for (int j = 0; j < UNROLL; ++j) {
        int idx = tileBase + t + j * 256;
        vx[j] = x4[idx];
        vk[j] = k4[idx];
    }

    unsigned long long w[UNROLL];
#pragma unroll
    for (int j = 0; j < UNROLL; ++j) {
        w[j] = ((unsigned long long)nib4(vx[j]) << base)
             | ((unsigned long long)nib4(vk[j]) << (32u + base));
    }
#pragma unroll
    for (int j = 0; j < UNROLL; ++j) w[j] |= __shfl_xor(w[j], 1);
#pragma unroll
    for (int j = 0; j < UNROLL; ++j) w[j] |= __shfl_xor(w[j], 2);
#pragma unroll
    for (int j = 0; j < UNROLL; ++j) w[j] |= __shfl_xor(w[j], 4);

#pragma unroll
    for (int j = 0; j < UNROLL; ++j) {
        unsigned xw = (unsigned)w[j];
        unsigned kw = (unsigned)(w[j] >> 32);

        unsigned ek   = rev8((kw >> 1) & 0xFFu);
        unsigned val  = 0x80u | (__builtin_bitreverse32((kw >> 9) & 0x7Fu) >> 25);
        unsigned s    = (ek - 127u) & 7u;
        unsigned kabs = val >> (7u - s);
        unsigned kfin = (kw & 1u) ? ((0u - kabs) & 0xFFu) : kabs;

        unsigned ex   = rev8((xw >> 1) & 0xFFu);
        unsigned enew = (ex + kfin) & 0xFFu;

        unsigned scaled = (xw & 1u) | (rev8(enew) << 1) | (xw & 0xFFFFFE00u);
        unsigned res    = ((kw & ~1u) == 0u) ? xw : scaled;

        vfloat4 out;
        out.x = (float)((res >> (base + 0u)) & 1u);
        out.y = (float)((res >> (base + 1u)) & 1u);
        out.z = (float)((res >> (base + 2u)) & 1u);
        out.w = (float)((res >> (base + 3u)) & 1u);
        __builtin_nontemporal_store(out, &o4[tileBase + t + j * 256]);
    }
}

extern "C" void kernel_launch(void* const* d_in, const int* in_sizes, int n_in,
                              void* d_out, int out_size, void* d_ws, size_t ws_size,
                              hipStream_t stream) {
    const uint4* x4 = (const uint4*)d_in[0];
    const uint4* k4 = (const uint4*)d_in[1];
    vfloat4* o4 = (vfloat4*)d_out;

    int n_elems = in_sizes[0];                  // N * 32 = 67,108,864
    int nvec    = n_elems / 4;                  // 16,777,216 float4 vectors
    int blocks  = nvec / (256 * UNROLL);        // exact: 16384 blocks

    spike_scale_kernel<<<blocks, 256, 0, stream>>>(x4, k4, o4);
}